// Round 3
// baseline (323.222 us; speedup 1.0000x reference)
//
#include <hip/hip_runtime.h>

// ---------------------------------------------------------------------------
// CustomCrossAttentionMinimal on MI355X (gfx950)
// b=16, i=4096, j=77, qd=320, cd=768, H=8, DH=40, inner=320
// ---------------------------------------------------------------------------

typedef _Float16 vh8 __attribute__((ext_vector_type(8)));
typedef _Float16 vh4 __attribute__((ext_vector_type(4)));
typedef float    vf4 __attribute__((ext_vector_type(4)));

#define NEGBIG  (-3.4028235e38f)
#define SCALE_F 0.15811388300841897f                 // 40^-0.5
#define SC2     (0.15811388300841897f * 1.4426950408889634f)  // fold log2(e)
#define INFF    (__builtin_inff())

__device__ __forceinline__ vh8 h8zero() {
  vh8 v;
#pragma unroll
  for (int i = 0; i < 8; ++i) v[i] = (_Float16)0.f;
  return v;
}
__device__ __forceinline__ vf4 f4zero() {
  vf4 v;
#pragma unroll
  for (int i = 0; i < 4; ++i) v[i] = 0.f;
  return v;
}
__device__ __forceinline__ float gelu_exact(float x) {
  return 0.5f * x * (1.0f + erff(x * 0.70710678118654752f));
}
__device__ __forceinline__ unsigned swzA(int row) {
  return (unsigned)(((row & 7) << 4) ^ (((row >> 3) & 1) << 5));
}
__device__ __forceinline__ void glds16(const void* g, void* l) {
  __builtin_amdgcn_global_load_lds((const __attribute__((address_space(1))) unsigned*)g,
                                   (__attribute__((address_space(3))) unsigned*)l, 16, 0, 0);
}

// ---------------------------------------------------------------------------
// Weight pre-transpose to fp16 [N][K]
// ---------------------------------------------------------------------------
__global__ __launch_bounds__(256) void transpose_kernel(
    const float* __restrict__ Wq, const float* __restrict__ Wk,
    const float* __restrict__ Wv, const float* __restrict__ Wo,
    _Float16* __restrict__ WqT, _Float16* __restrict__ WkvT, _Float16* __restrict__ WoT)
{
  int idx = blockIdx.x * 256 + threadIdx.x;
  if (idx < 102400) {
    int n = idx / 320, k = idx - n * 320;
    WqT[idx] = (_Float16)Wq[k * 320 + n];
    return;
  }
  idx -= 102400;
  if (idx < 491520) {
    int n = idx / 768, k = idx - n * 768;
    float v = (n < 320) ? Wk[k * 320 + n] : Wv[k * 320 + (n - 320)];
    WkvT[idx] = (_Float16)v;
    return;
  }
  idx -= 491520;
  if (idx < 102400) {
    int n = idx / 320, k = idx - n * 320;
    WoT[idx] = (_Float16)Wo[k * 320 + n];
  }
}

// ---------------------------------------------------------------------------
// V^T pre-swizzled global: vTg[b][h][d(48)][chunk c(16)][e(8)] fp16
// content at (d,c) = V^T[d][ 8*(c ^ (swzA(d)>>4)) .. +8 ]
// ---------------------------------------------------------------------------
__global__ __launch_bounds__(256) void vtrans_kernel(
    const _Float16* __restrict__ vf, unsigned* __restrict__ vTg32)
{
  const int b = blockIdx.x, h = blockIdx.y, t = threadIdx.x;
  unsigned* out = vTg32 + (size_t)(b * 8 + h) * 3072;
#pragma unroll
  for (int p = 0; p < 12; ++p) {
    int idx = t + p * 256;            // u32 index 0..3071
    int d = idx >> 6;                 // 64 u32 per d-row
    int u = idx & 63;
    int c = u >> 2, pr = u & 3;
    int sd = (int)(swzA(d) >> 4);
    int j0 = ((c ^ sd) << 3) + pr * 2;
    unsigned lo = 0, hi = 0;
    if (d < 40) {
      if (j0 < 77)     lo = *(const unsigned short*)(vf + (size_t)(b * 77 + j0) * 640 + h * 40 + d);
      if (j0 + 1 < 77) hi = *(const unsigned short*)(vf + (size_t)(b * 77 + j0 + 1) * 640 + h * 40 + d);
    }
    out[idx] = lo | (hi << 16);
  }
}

// ---------------------------------------------------------------------------
// fp16-MFMA GEMM:  C[M,N] = A[M,K] @ Bt[N,K]^T (+bias)
// BM=128, BN=160, BK=64, 4 waves. B (and fp16-A) staged via global_load_lds
// with XOR-pre-swizzled source addresses; LDS stays linear, reads XOR.
// ---------------------------------------------------------------------------
template<bool A_HALF, bool BIAS, bool OUT_F32>
__global__ __launch_bounds__(256) void gemm_kernel(
    const void* __restrict__ Ap, const _Float16* __restrict__ Bt,
    const float* __restrict__ bias, void* __restrict__ Cp,
    int M, int N, int K)
{
  __shared__ _Float16 As[128 * 64];   // [row][k] pitch 128B, content-swizzled (row&7)<<4
  __shared__ _Float16 Bs[160 * 64];   // [n][k]  pitch 128B, content-swizzled (n&7)<<4
  const int t    = threadIdx.x;
  const int lane = t & 63;
  const int wave = t >> 6;
  const int m0 = blockIdx.x * 128;
  const int n0 = blockIdx.y * 160;
  const int l15 = lane & 15, l4 = lane >> 4;
  const int wbase = t & ~63;

  vf4 acc[2][10];
#pragma unroll
  for (int a = 0; a < 2; ++a)
#pragma unroll
    for (int bq = 0; bq < 10; ++bq) acc[a][bq] = f4zero();

  for (int k0 = 0; k0 < K; k0 += 64) {
    __syncthreads();
    if (A_HALF) {
      const _Float16* A = (const _Float16*)Ap;
#pragma unroll
      for (int p = 0; p < 4; ++p) {
        int idx = t + p * 256;        // chunk 0..1023
        int row = idx >> 3, c8 = idx & 7;
        const _Float16* src = A + (size_t)(m0 + row) * K + k0 + ((c8 ^ (row & 7)) << 3);
        glds16(src, (char*)As + (size_t)(p * 256 + wbase) * 16);
      }
    } else {
#pragma unroll
      for (int p = 0; p < 8; ++p) {
        int idx = t + p * 256;        // 0..2047
        int row = idx >> 4, g4 = idx & 15;
        int m = m0 + row;
        vh4 hw;
        hw[0] = (_Float16)0.f; hw[1] = (_Float16)0.f; hw[2] = (_Float16)0.f; hw[3] = (_Float16)0.f;
        if (m < M) {
          const float* ap = (const float*)Ap + (size_t)m * K + k0 + g4 * 4;
          float4 f = *(const float4*)ap;
          hw[0] = (_Float16)f.x; hw[1] = (_Float16)f.y; hw[2] = (_Float16)f.z; hw[3] = (_Float16)f.w;
        }
        unsigned byte = (unsigned)(row * 128 + g4 * 8) ^ (unsigned)((row & 7) << 4);
        *(vh4*)((char*)As + byte) = hw;
      }
    }
    // B tile: 160 n-rows x 64 k = 1280 chunks via global_load_lds
#pragma unroll
    for (int p = 0; p < 5; ++p) {
      int idx = t + p * 256;          // 0..1279
      int n = idx >> 3, c8 = idx & 7;
      const _Float16* src = Bt + (size_t)(n0 + n) * K + k0 + ((c8 ^ (n & 7)) << 3);
      glds16(src, (char*)Bs + (size_t)(p * 256 + wbase) * 16);
    }
    __syncthreads();
#pragma unroll
    for (int ks = 0; ks < 2; ++ks) {
      vh8 av[2];
#pragma unroll
      for (int mt = 0; mt < 2; ++mt) {
        int row = wave * 32 + mt * 16 + l15;
        unsigned byte = (unsigned)(row * 128 + (ks * 32 + l4 * 8) * 2) ^ (unsigned)((row & 7) << 4);
        av[mt] = *(const vh8*)((const char*)As + byte);
      }
#pragma unroll
      for (int nt = 0; nt < 10; ++nt) {
        int n = nt * 16 + l15;
        unsigned byte = (unsigned)(n * 128 + (ks * 32 + l4 * 8) * 2) ^ (unsigned)((n & 7) << 4);
        vh8 bv = *(const vh8*)((const char*)Bs + byte);
        acc[0][nt] = __builtin_amdgcn_mfma_f32_16x16x32_f16(av[0], bv, acc[0][nt], 0, 0, 0);
        acc[1][nt] = __builtin_amdgcn_mfma_f32_16x16x32_f16(av[1], bv, acc[1][nt], 0, 0, 0);
      }
    }
  }
#pragma unroll
  for (int mt = 0; mt < 2; ++mt)
#pragma unroll
    for (int nt = 0; nt < 10; ++nt) {
      int n = n0 + nt * 16 + l15;
#pragma unroll
      for (int r = 0; r < 4; ++r) {
        int m = m0 + wave * 32 + mt * 16 + l4 * 4 + r;
        if (m < M) {
          float v = acc[mt][nt][r];
          if (BIAS) v += bias[n];
          if (OUT_F32) ((float*)Cp)[(size_t)m * N + n] = v;
          else ((_Float16*)Cp)[(size_t)m * N + n] = (_Float16)v;
        }
      }
    }
}

// ---------------------------------------------------------------------------
// Progress classifier
// ---------------------------------------------------------------------------
__global__ __launch_bounds__(256) void classifier_kernel(
    const float* __restrict__ progress,
    const float* __restrict__ emb1, const float* __restrict__ emb2,
    const float* __restrict__ Wc1, const float* __restrict__ bc1,
    const float* __restrict__ Wc2, const float* __restrict__ bc2,
    float* __restrict__ pcb)
{
  __shared__ float g[512];
  __shared__ float h1[512];
  __shared__ float lg[16];
  const int b = blockIdx.x;
  const int t = threadIdx.x;

  float pr = progress[b];
  int xstep = (int)rintf(pr * 1000.0f);
  if (xstep > 999) xstep = 999;
  int a = xstep / 20;
  int r = xstep - a * 20;

  for (int d = t; d < 512; d += 256) {
    float e = emb1[a * 512 + d] + emb2[r * 512 + d];
    g[d] = gelu_exact(e);
  }
  __syncthreads();
  for (int n = t; n < 512; n += 256) {
    float acc = bc1[n];
    for (int d = 0; d < 512; ++d) acc = fmaf(g[d], Wc1[d * 512 + n], acc);
    h1[n] = gelu_exact(acc);
  }
  __syncthreads();
  if (t < 16) {
    float acc = bc2[t];
    for (int d = 0; d < 512; ++d) acc = fmaf(h1[d], Wc2[d * 16 + t], acc);
    lg[t] = acc;
  }
  __syncthreads();
  if (t < 8) {
    float a0 = lg[2 * t], a1 = lg[2 * t + 1];
    float mx = fmaxf(a0, a1);
    float e0 = __expf(a0 - mx), e1 = __expf(a1 - mx);
    float inv = 1.0f / (e0 + e1);
    pcb[(b * 8 + t) * 2 + 0] = e0 * inv;
    pcb[(b * 8 + t) * 2 + 1] = e1 * inv;
  }
}

// ---------------------------------------------------------------------------
// Masked Sum/SumSq of sim (fp64, per-wave partials). Grid (64,16,8).
// No LDS staging: K B-frags and masks read per-lane from L2-resident buffers.
// ---------------------------------------------------------------------------
__global__ __launch_bounds__(256) void std_kernel(
    const _Float16* __restrict__ q, const _Float16* __restrict__ kf,
    const int* __restrict__ ctypes, double* __restrict__ partials)
{
  const int t = threadIdx.x, lane = t & 63, wave = t >> 6;
  const int it = blockIdx.x, b = blockIdx.y, h = blockIdx.z;
  const int i0 = it * 64;
  const int l15 = lane & 15, l4 = lane >> 4;

  int qrow = b * 4096 + i0 + wave * 16 + l15;
  const _Float16* qb = q + (size_t)qrow * 320 + h * 40;
  vh8 a0 = *(const vh8*)(qb + l4 * 8);
  vh8 a1 = h8zero();
  if (l4 == 0) a1 = *(const vh8*)(qb + 32);

  double S = 0.0, S2 = 0.0;
#pragma unroll
  for (int jt = 0; jt < 5; ++jt) {
    int j = jt * 16 + l15;
    bool valid = (j < 77);
    vh8 b0 = h8zero(), b1 = h8zero();
    int ctj = -1;
    if (valid) {
      const _Float16* kp = kf + (size_t)(b * 77 + j) * 640 + h * 40;
      b0 = *(const vh8*)(kp + l4 * 8);
      if (l4 == 0) b1 = *(const vh8*)(kp + 32);
      ctj = ctypes[b * 77 + j];
    }
    vf4 s = f4zero();
    s = __builtin_amdgcn_mfma_f32_16x16x32_f16(a0, b0, s, 0, 0, 0);
    s = __builtin_amdgcn_mfma_f32_16x16x32_f16(a1, b1, s, 0, 0, 0);
    if (ctj >= 2) {
#pragma unroll
      for (int r = 0; r < 4; ++r) {
        double sv = (double)s[r];
        S += sv; S2 += sv * sv;
      }
    }
  }
#pragma unroll
  for (int off = 32; off > 0; off >>= 1) {
    S += __shfl_xor(S, off);
    S2 += __shfl_xor(S2, off);
  }
  if (lane == 0) {
    int idx = (((b * 64 + it) * 8) + h) * 4 + wave;
    partials[2 * idx + 0] = S;
    partials[2 * idx + 1] = S2;
  }
}

__global__ __launch_bounds__(256) void finalize_kernel(
    const double* __restrict__ partials, const int* __restrict__ ctypes,
    float* __restrict__ ssb)
{
  __shared__ double rs[256];
  __shared__ double rs2[256];
  __shared__ int rc[256];
  const int t = threadIdx.x;
  double S = 0.0, S2 = 0.0;
#pragma unroll
  for (int p = 0; p < 128; ++p) {
    int idx = t + p * 256;
    S += partials[2 * idx + 0];
    S2 += partials[2 * idx + 1];
  }
  int c = 0;
#pragma unroll
  for (int p = 0; p < 5; ++p) {
    int idx = t + p * 256;
    if (idx < 1232) c += (ctypes[idx] >= 2) ? 1 : 0;
  }
  rs[t] = S; rs2[t] = S2; rc[t] = c;
  __syncthreads();
  for (int off = 128; off > 0; off >>= 1) {
    if (t < off) { rs[t] += rs[t + off]; rs2[t] += rs2[t + off]; rc[t] += rc[t + off]; }
    __syncthreads();
  }
  if (t == 0) {
    double n = (double)rc[0] * 8.0 * 4096.0;
    double mean = rs[0] / n;
    double var = (rs2[0] - n * mean * mean) / (n - 1.0);
    ssb[0] = (float)sqrt(var > 0.0 ? var : 0.0);
  }
}

// ---------------------------------------------------------------------------
// lmask precompute: packed bits lmp[row][qd], qd=j&3, bit m=j>>2.
// ---------------------------------------------------------------------------
__global__ __launch_bounds__(256) void lmask_kernel(
    const float* __restrict__ cam, const int* __restrict__ ctypes,
    const float* __restrict__ ssb, const float* __restrict__ strengthp,
    unsigned* __restrict__ lmp)
{
  __shared__ float camt[64 * 81];
  __shared__ unsigned char gmv[96];
  __shared__ unsigned char m2v[96];
  const int t = threadIdx.x;
  const int it = blockIdx.x, b = blockIdx.y;
  const int i0 = it * 64;

  if (t < 96) {
    int j = t;
    int ct = (j < 77) ? ctypes[b * 77 + j] : -1;
    gmv[j] = (j < 77 && ct >= 0 && ct < 2) ? 1 : 0;
    m2v[j] = (j < 77 && ct >= 2) ? 1 : 0;
  }
#pragma unroll
  for (int p = 0; p < 20; ++p) {
    int idx = t + p * 256;
    int row = idx / 80;
    int j = idx - row * 80;
    camt[row * 81 + j] = (j < 77) ? cam[((size_t)b * 4096 + i0 + row) * 77 + j] : 0.f;
  }
  __syncthreads();

  const float ss = ssb[0];
  const float st = strengthp[0];
  int row = t >> 2, qd = t & 3;
  float wfv[20];
  float wmax = 0.f, wsum = 0.f;
#pragma unroll
  for (int m = 0; m < 20; ++m) {
    int j = qd + 4 * m;
    float wf = 0.f;
    if (j < 77 && m2v[j]) wf = (camt[row * 81 + j] * ss) * st;   // ref assoc order
    wfv[m] = wf;
    wmax = fmaxf(wmax, wf);
    wsum += wf;
  }
  wmax = fmaxf(wmax, __shfl_xor(wmax, 1));
  wmax = fmaxf(wmax, __shfl_xor(wmax, 2));
  wsum += __shfl_xor(wsum, 1);
  wsum += __shfl_xor(wsum, 2);
  float thr = fmaxf(wmax, 0.001f) - 0.0001f;
  bool ug = (wsum == 0.f);
  unsigned wbits = 0u;
#pragma unroll
  for (int m = 0; m < 20; ++m) {
    int j = qd + 4 * m;
    bool lv = (wfv[m] >= thr) || (ug && (j < 77) && gmv[j]);
    if (lv) wbits |= (1u << m);
  }
  lmp[((size_t)b * 4096 + i0 + row) * 4 + qd] = wbits;
}

// ---------------------------------------------------------------------------
// Fused attention: grid (64,16,8), 256 thr. Swapped QK^T (lane owns a q-row),
// in-lane dual softmax, vT via pre-swizzled global_load_lds, PV MFMA.
// ---------------------------------------------------------------------------
__global__ __launch_bounds__(256) void attn_kernel(
    const _Float16* __restrict__ q, const _Float16* __restrict__ kf,
    const unsigned* __restrict__ vTg32, const int* __restrict__ ctypes,
    const float* __restrict__ pcb, const unsigned* __restrict__ lmp,
    _Float16* __restrict__ ho)
{
  __shared__ _Float16 vT[48 * 128];        // [d][j] pitch 256B, XOR swzA(d)
  __shared__ _Float16 attnbuf[64 * 128];   // [row][j] pitch 256B, XOR swzA(row)
  __shared__ unsigned lmw[256];
  __shared__ float gbf[96];
  __shared__ float nbf[96];

  const int t = threadIdx.x, lane = t & 63, wave = t >> 6;
  const int it = blockIdx.x, b = blockIdx.y, h = blockIdx.z;
  const int i0 = it * 64;
  const int l15 = lane & 15, l4 = lane >> 4;

  if (t < 96) {
    int j = t;
    bool valid = (j < 77);
    int ct = valid ? ctypes[b * 77 + j] : -1;
    bool gm = valid && ct >= 0 && ct < 2;
    gbf[j] = gm ? 0.f : (valid ? NEGBIG : -INFF);
    nbf[j] = valid ? NEGBIG : -INFF;
  }
  lmw[t] = lmp[((size_t)b * 4096 + i0) * 4 + t];

  // vT: 768 16B chunks via global_load_lds (content pre-swizzled in vTg)
  {
    const unsigned* src0 = vTg32 + (size_t)(b * 8 + h) * 3072;
#pragma unroll
    for (int p = 0; p < 3; ++p) {
      int idx = t + p * 256;
      glds16(src0 + idx * 4, (char*)vT + (size_t)(p * 256 + (t & ~63)) * 16);
    }
  }
  // zero attnbuf pad j in [80,96)
#pragma unroll
  for (int p = 0; p < 2; ++p) {
    int idx = t + p * 256;
    int row = idx >> 3, c = idx & 7;
    unsigned byte = (unsigned)(row * 256 + 160 + c * 4) ^ swzA(row);
    *(unsigned*)((char*)attnbuf + byte) = 0u;
  }

  // Q frag (B operand), K frags (A operand) — per-lane global loads
  int qrow = b * 4096 + i0 + wave * 16 + l15;
  const _Float16* qbp = q + (size_t)qrow * 320 + h * 40;
  vh8 qf0 = *(const vh8*)(qbp + l4 * 8);
  vh8 qf1 = h8zero();
  if (l4 == 0) qf1 = *(const vh8*)(qbp + 32);

  vf4 sacc[5];
#pragma unroll
  for (int jt = 0; jt < 5; ++jt) sacc[jt] = f4zero();
#pragma unroll
  for (int jt = 0; jt < 5; ++jt) {
    int j = jt * 16 + l15;
    vh8 k0v = h8zero(), k1v = h8zero();
    if (j < 77) {
      const _Float16* kp = kf + (size_t)(b * 77 + j) * 640 + h * 40;
      k0v = *(const vh8*)(kp + l4 * 8);
      if (l4 == 0) k1v = *(const vh8*)(kp + 32);
    }
    // swapped: A=K, B=Q  ->  C[j][q]; lane holds q = wave*16+l15, j = jt*16+l4*4+r
    sacc[jt] = __builtin_amdgcn_mfma_f32_16x16x32_f16(k0v, qf0, sacc[jt], 0, 0, 0);
    sacc[jt] = __builtin_amdgcn_mfma_f32_16x16x32_f16(k1v, qf1, sacc[jt], 0, 0, 0);
  }

  __syncthreads();   // vT, gbf, nbf, lmw, pad-zero ready

  // in-lane dual softmax over this lane's q-row
  const float pc0 = pcb[(b * 8 + h) * 2 + 0];
  const float pc1 = pcb[(b * 8 + h) * 2 + 1];
  const int myrow = wave * 16 + l15;
  unsigned wbits[4];
#pragma unroll
  for (int r = 0; r < 4; ++r) wbits[r] = lmw[myrow * 4 + r];

  float gv[5][4], lv[5][4];
  float mg = -INFF, ml = -INFF;
#pragma unroll
  for (int jt = 0; jt < 5; ++jt) {
    int jbase = jt * 16 + l4 * 4;
    float4 gb4 = *(const float4*)&gbf[jbase];
    float4 nb4 = *(const float4*)&nbf[jbase];
    const float* gbp = (const float*)&gb4;
    const float* nbp = (const float*)&nb4;
#pragma unroll
    for (int r = 0; r < 4; ++r) {
      float sv = sacc[jt][r];
      float g = fmaf(sv, SC2, gbp[r]);
      unsigned bit = (wbits[r] >> (jt * 4 + l4)) & 1u;
      float l = fmaf(sv, SC2, bit ? 0.f : nbp[r]);
      gv[jt][r] = g; lv[jt][r] = l;
      mg = fmaxf(mg, g); ml = fmaxf(ml, l);
    }
  }
  mg = fmaxf(mg, __shfl_xor(mg, 16)); mg = fmaxf(mg, __shfl_xor(mg, 32));
  ml = fmaxf(ml, __shfl_xor(ml, 16)); ml = fmaxf(ml, __shfl_xor(ml, 32));
  float sG = 0.f, sL = 0.f;
#pragma unroll
  for (int jt = 0; jt < 5; ++jt)
#pragma unroll
    for (int r = 0; r < 4; ++r) {
      float eg = exp2f(gv[jt][r] - mg);
      float el = exp2f(lv[jt][r] - ml);
      gv[jt][r] = eg; lv[jt][r] = el;
      sG += eg; sL += el;
    }
  sG += __shfl_xor(sG, 16); sG += __shfl_xor(sG, 32);
  sL += __shfl_xor(sL, 16); sL += __shfl_xor(sL, 32);
  float rG = pc0 / sG, rL = pc1 / sL;
  {
    unsigned swz = swzA(myrow);
    unsigned rowbase = (unsigned)(myrow * 256);
#pragma unroll
    for (int jt = 0; jt < 5; ++jt) {
      vh4 w;
#pragma unroll
      for (int r = 0; r < 4; ++r)
        w[r] = (_Float16)fmaf(gv[jt][r], rG, lv[jt][r] * rL);
      unsigned byte = (rowbase + (unsigned)((jt * 16 + l4 * 4) * 2)) ^ swz;
      *(vh4*)((char*)attnbuf + byte) = w;
    }
  }
  __syncthreads();

  // PV MFMA, store ho
  vf4 oacc[3];
#pragma unroll
  for (int nt = 0; nt < 3; ++nt) oacc[nt] = f4zero();
#pragma unroll
  for (int ks = 0; ks < 3; ++ks) {
    int arow = wave * 16 + l15;
    unsigned abyte = (unsigned)(arow * 256 + (ks * 32 + l4 * 8) * 2) ^ swzA(arow);
    vh8 pa = *(const vh8*)((const char*)attnbuf + abyte);
#pragma unroll
    for (int nt = 0; nt < 3; ++nt) {
      int n = nt * 16 + l15;
      unsigned byte = (unsigned)(n * 256 + (ks * 32 + l4 * 8) * 2) ^ swzA(n);
      vh8 vb = *(const vh8*)((const char*)vT + byte);
      oacc[nt] = __builtin_amdgcn_mfma_f32_16x16x32_f16(pa, vb, oacc[nt], 0, 0, 0);
    }
  }
#pragma unroll
  for (int nt = 0; nt < 3; ++nt) {
    int d = nt * 16 + l15;
    if (d < 40) {
#pragma unroll
      for (int r = 0; r < 4; ++r) {
        int m = wave * 16 + l4 * 4 + r;
        ho[(size_t)(b * 4096 + i0 + m) * 320 + h * 40 + d] = (_Float16)oacc[nt][r];
      }
    }
  }
}

// ---------------------------------------------------------------------------
extern "C" void kernel_launch(void* const* d_in, const int* in_sizes, int n_in,
                              void* d_out, int out_size, void* d_ws, size_t ws_size,
                              hipStream_t stream)
{
  const float* x        = (const float*)d_in[0];
  const float* embs     = (const float*)d_in[1];
  const float* cam      = (const float*)d_in[2];
  const float* progress = (const float*)d_in[3];
  const float* strength = (const float*)d_in[4];
  const float* Wq       = (const float*)d_in[5];
  const float* Wk       = (const float*)d_in[6];
  const float* Wv       = (const float*)d_in[7];
  const float* Wo       = (const float*)d_in[8];
  const float* bo       = (const float*)d_in[9];
  const float* emb1     = (const float*)d_in[10];
  const float* emb2     = (const float*)d_in[11];
  const float* Wc1      = (const float*)d_in[12];
  const float* bc1      = (const float*)d_in[13];
  const float* Wc2      = (const float*)d_in[14];
  const float* bc2      = (const float*)d_in[15];
  const int*   ctypes   = (const int*)d_in[16];

  char* w = (char*)d_ws;
  auto alloc = [&](size_t bytes) { char* p = w; w += (bytes + 255) & ~(size_t)255; return p; };
  _Float16* qb    = (_Float16*)alloc(65536ull * 320 * 2);   // 40 MiB
  _Float16* hob   = (_Float16*)alloc(65536ull * 320 * 2);   // 40 MiB
  _Float16* kvb   = (_Float16*)alloc(1232ull * 640 * 2);    // 1.5 MiB
  unsigned* vTg   = (unsigned*)alloc(128ull * 3072 * 4);    // 1.5 MiB
  _Float16* WqT   = (_Float16*)alloc(320ull * 320 * 2);
  _Float16* WkvT  = (_Float16*)alloc(640ull * 768 * 2);
  _Float16* WoT   = (_Float16*)alloc(320ull * 320 * 2);
  unsigned* lmp   = (unsigned*)alloc(65536ull * 4 * 4);     // 1 MiB
  float*    pcb   = (float*)alloc(256 * 4);
  double*   part  = (double*)alloc(32768ull * 2 * 8);       // 512 KiB
  float*    ssb   = (float*)alloc(256);

  transpose_kernel<<<2720, 256, 0, stream>>>(Wq, Wk, Wv, Wo, WqT, WkvT, WoT);
  classifier_kernel<<<16, 256, 0, stream>>>(progress, emb1, emb2, Wc1, bc1, Wc2, bc2, pcb);
  gemm_kernel<false, false, false><<<dim3(512, 2), 256, 0, stream>>>(x, WqT, nullptr, qb, 65536, 320, 320);
  gemm_kernel<false, false, false><<<dim3(10, 4), 256, 0, stream>>>(embs, WkvT, nullptr, kvb, 1232, 640, 768);
  vtrans_kernel<<<dim3(16, 8), 256, 0, stream>>>(kvb + 320, vTg);
  std_kernel<<<dim3(64, 16, 8), 256, 0, stream>>>(qb, kvb, ctypes, part);
  finalize_kernel<<<1, 256, 0, stream>>>(part, ctypes, ssb);
  lmask_kernel<<<dim3(64, 16), 256, 0, stream>>>(cam, ctypes, ssb, strength, lmp);
  attn_kernel<<<dim3(64, 16, 8), 256, 0, stream>>>(qb, kvb, vTg, ctypes, pcb, lmp, hob);
  gemm_kernel<true, true, true><<<dim3(512, 2), 256, 0, stream>>>(hob, WoT, bo, (float*)d_out, 65536, 320, 320);
}

// Round 4
// 294.756 us; speedup vs baseline: 1.0966x; 1.0966x over previous
//
#include <hip/hip_runtime.h>

// ---------------------------------------------------------------------------
// CustomCrossAttentionMinimal on MI355X (gfx950)
// b=16, i=4096, j=77, qd=320, cd=768, H=8, DH=40, inner=320
// ---------------------------------------------------------------------------

typedef _Float16 vh8 __attribute__((ext_vector_type(8)));
typedef _Float16 vh4 __attribute__((ext_vector_type(4)));
typedef float    vf4 __attribute__((ext_vector_type(4)));

#define NEGBIG  (-3.4028235e38f)
#define SCALE_F 0.15811388300841897f                 // 40^-0.5
#define SC2     (0.15811388300841897f * 1.4426950408889634f)  // fold log2(e)
#define INFF    (__builtin_inff())

__device__ __forceinline__ vh8 h8zero() {
  vh8 v;
#pragma unroll
  for (int i = 0; i < 8; ++i) v[i] = (_Float16)0.f;
  return v;
}
__device__ __forceinline__ vf4 f4zero() {
  vf4 v;
#pragma unroll
  for (int i = 0; i < 4; ++i) v[i] = 0.f;
  return v;
}
__device__ __forceinline__ float gelu_exact(float x) {
  return 0.5f * x * (1.0f + erff(x * 0.70710678118654752f));
}
__device__ __forceinline__ unsigned swzA(int row) {
  return (unsigned)(((row & 7) << 4) ^ (((row >> 3) & 1) << 5));
}
__device__ __forceinline__ void glds16(const void* g, void* l) {
  __builtin_amdgcn_global_load_lds((const __attribute__((address_space(1))) unsigned*)g,
                                   (__attribute__((address_space(3))) unsigned*)l, 16, 0, 0);
}

// ---------------------------------------------------------------------------
// Weight pre-transpose to fp16 [N][K]
// ---------------------------------------------------------------------------
__global__ __launch_bounds__(256) void transpose_kernel(
    const float* __restrict__ Wq, const float* __restrict__ Wk,
    const float* __restrict__ Wv, const float* __restrict__ Wo,
    _Float16* __restrict__ WqT, _Float16* __restrict__ WkvT, _Float16* __restrict__ WoT)
{
  int idx = blockIdx.x * 256 + threadIdx.x;
  if (idx < 102400) {
    int n = idx / 320, k = idx - n * 320;
    WqT[idx] = (_Float16)Wq[k * 320 + n];
    return;
  }
  idx -= 102400;
  if (idx < 491520) {
    int n = idx / 768, k = idx - n * 768;
    float v = (n < 320) ? Wk[k * 320 + n] : Wv[k * 320 + (n - 320)];
    WkvT[idx] = (_Float16)v;
    return;
  }
  idx -= 491520;
  if (idx < 102400) {
    int n = idx / 320, k = idx - n * 320;
    WoT[idx] = (_Float16)Wo[k * 320 + n];
  }
}

// ---------------------------------------------------------------------------
// V^T pre-swizzled global: vTg[b][h][d(48)][chunk c(16)][e(8)] fp16
// ---------------------------------------------------------------------------
__global__ __launch_bounds__(256) void vtrans_kernel(
    const _Float16* __restrict__ vf, unsigned* __restrict__ vTg32)
{
  const int b = blockIdx.x, h = blockIdx.y, t = threadIdx.x;
  unsigned* out = vTg32 + (size_t)(b * 8 + h) * 3072;
#pragma unroll
  for (int p = 0; p < 12; ++p) {
    int idx = t + p * 256;            // u32 index 0..3071
    int d = idx >> 6;                 // 64 u32 per d-row
    int u = idx & 63;
    int c = u >> 2, pr = u & 3;
    int sd = (int)(swzA(d) >> 4);
    int j0 = ((c ^ sd) << 3) + pr * 2;
    unsigned lo = 0, hi = 0;
    if (d < 40) {
      if (j0 < 77)     lo = *(const unsigned short*)(vf + (size_t)(b * 77 + j0) * 640 + h * 40 + d);
      if (j0 + 1 < 77) hi = *(const unsigned short*)(vf + (size_t)(b * 77 + j0 + 1) * 640 + h * 40 + d);
    }
    out[idx] = lo | (hi << 16);
  }
}

// ---------------------------------------------------------------------------
// KV GEMM: C[M,N] = A[M,K] @ Bt[N,K]^T ; BM=128, BN=160, BK=64
// ---------------------------------------------------------------------------
__global__ __launch_bounds__(256) void kv_gemm_kernel(
    const float* __restrict__ Ap, const _Float16* __restrict__ Bt,
    _Float16* __restrict__ Cp, int M, int N, int K)
{
  __shared__ _Float16 As[128 * 64];
  __shared__ _Float16 Bs[160 * 64];
  const int t = threadIdx.x, lane = t & 63, wave = t >> 6;
  const int m0 = blockIdx.x * 128;
  const int n0 = blockIdx.y * 160;
  const int l15 = lane & 15, l4 = lane >> 4;
  const int wbase = t & ~63;

  vf4 acc[2][10];
#pragma unroll
  for (int a = 0; a < 2; ++a)
#pragma unroll
    for (int bq = 0; bq < 10; ++bq) acc[a][bq] = f4zero();

  for (int k0 = 0; k0 < K; k0 += 64) {
    __syncthreads();
#pragma unroll
    for (int p = 0; p < 8; ++p) {
      int idx = t + p * 256;
      int row = idx >> 4, g4 = idx & 15;
      int m = m0 + row;
      vh4 hw;
      hw[0] = (_Float16)0.f; hw[1] = (_Float16)0.f; hw[2] = (_Float16)0.f; hw[3] = (_Float16)0.f;
      if (m < M) {
        const float* ap = Ap + (size_t)m * K + k0 + g4 * 4;
        float4 f = *(const float4*)ap;
        hw[0] = (_Float16)f.x; hw[1] = (_Float16)f.y; hw[2] = (_Float16)f.z; hw[3] = (_Float16)f.w;
      }
      unsigned byte = (unsigned)(row * 128 + g4 * 8) ^ (unsigned)((row & 7) << 4);
      *(vh4*)((char*)As + byte) = hw;
    }
#pragma unroll
    for (int p = 0; p < 5; ++p) {
      int idx = t + p * 256;
      int n = idx >> 3, c8 = idx & 7;
      const _Float16* src = Bt + (size_t)(n0 + n) * K + k0 + ((c8 ^ (n & 7)) << 3);
      glds16(src, (char*)Bs + (size_t)(p * 256 + wbase) * 16);
    }
    __syncthreads();
#pragma unroll
    for (int ks = 0; ks < 2; ++ks) {
      vh8 av[2];
#pragma unroll
      for (int mt = 0; mt < 2; ++mt) {
        int row = wave * 32 + mt * 16 + l15;
        unsigned byte = (unsigned)(row * 128 + (ks * 32 + l4 * 8) * 2) ^ (unsigned)((row & 7) << 4);
        av[mt] = *(const vh8*)((const char*)As + byte);
      }
#pragma unroll
      for (int nt = 0; nt < 10; ++nt) {
        int n = nt * 16 + l15;
        unsigned byte = (unsigned)(n * 128 + (ks * 32 + l4 * 8) * 2) ^ (unsigned)((n & 7) << 4);
        vh8 bv = *(const vh8*)((const char*)Bs + byte);
        acc[0][nt] = __builtin_amdgcn_mfma_f32_16x16x32_f16(av[0], bv, acc[0][nt], 0, 0, 0);
        acc[1][nt] = __builtin_amdgcn_mfma_f32_16x16x32_f16(av[1], bv, acc[1][nt], 0, 0, 0);
      }
    }
  }
#pragma unroll
  for (int mt = 0; mt < 2; ++mt)
#pragma unroll
    for (int nt = 0; nt < 10; ++nt) {
      int n = n0 + nt * 16 + l15;
#pragma unroll
      for (int r = 0; r < 4; ++r) {
        int m = m0 + wave * 32 + mt * 16 + l4 * 4 + r;
        if (m < M) Cp[(size_t)m * N + n] = (_Float16)acc[mt][nt][r];
      }
    }
}

// ---------------------------------------------------------------------------
// Progress classifier
// ---------------------------------------------------------------------------
__global__ __launch_bounds__(256) void classifier_kernel(
    const float* __restrict__ progress,
    const float* __restrict__ emb1, const float* __restrict__ emb2,
    const float* __restrict__ Wc1, const float* __restrict__ bc1,
    const float* __restrict__ Wc2, const float* __restrict__ bc2,
    float* __restrict__ pcb)
{
  __shared__ float g[512];
  __shared__ float h1[512];
  __shared__ float lg[16];
  const int b = blockIdx.x;
  const int t = threadIdx.x;

  float pr = progress[b];
  int xstep = (int)rintf(pr * 1000.0f);
  if (xstep > 999) xstep = 999;
  int a = xstep / 20;
  int r = xstep - a * 20;

  for (int d = t; d < 512; d += 256) {
    float e = emb1[a * 512 + d] + emb2[r * 512 + d];
    g[d] = gelu_exact(e);
  }
  __syncthreads();
  for (int n = t; n < 512; n += 256) {
    float acc = bc1[n];
    for (int d = 0; d < 512; ++d) acc = fmaf(g[d], Wc1[d * 512 + n], acc);
    h1[n] = gelu_exact(acc);
  }
  __syncthreads();
  if (t < 16) {
    float acc = bc2[t];
    for (int d = 0; d < 512; ++d) acc = fmaf(h1[d], Wc2[d * 16 + t], acc);
    lg[t] = acc;
  }
  __syncthreads();
  if (t < 8) {
    float a0 = lg[2 * t], a1 = lg[2 * t + 1];
    float mx = fmaxf(a0, a1);
    float e0 = __expf(a0 - mx), e1 = __expf(a1 - mx);
    float inv = 1.0f / (e0 + e1);
    pcb[(b * 8 + t) * 2 + 0] = e0 * inv;
    pcb[(b * 8 + t) * 2 + 1] = e1 * inv;
  }
}

// ---------------------------------------------------------------------------
// qstd: Q-proj GEMM for a 64-row tile (q kept in LDS, also written to global)
// followed by masked Sum/SumSq of sim over all 8 heads. Grid (64,16).
// ---------------------------------------------------------------------------
__global__ __launch_bounds__(256) void qstd_kernel(
    const float* __restrict__ x, const _Float16* __restrict__ WqT,
    const _Float16* __restrict__ kf, const int* __restrict__ ctypes,
    _Float16* __restrict__ qb, double* __restrict__ partials)
{
  __shared__ _Float16 xs[64 * 64];      // [row][k] pitch 128B, XOR swzA(row)
  __shared__ _Float16 qls[64 * 320];    // [row][n] pitch 640B, XOR swzA(row) (40KB)
  const int t = threadIdx.x, lane = t & 63, wave = t >> 6;
  const int it = blockIdx.x, b = blockIdx.y;
  const int i0 = it * 64;
  const int l15 = lane & 15, l4 = lane >> 4;
  const size_t grow0 = (size_t)b * 4096 + i0;

  vf4 acc[4][5];
#pragma unroll
  for (int a = 0; a < 4; ++a)
#pragma unroll
    for (int bq = 0; bq < 5; ++bq) acc[a][bq] = f4zero();

  for (int k0 = 0; k0 < 320; k0 += 64) {
    __syncthreads();
    // stage x tile 64x64 -> fp16
#pragma unroll
    for (int p = 0; p < 4; ++p) {
      int idx = t + p * 256;          // 0..1023
      int row = idx >> 4, g4 = idx & 15;
      const float* ap = x + (grow0 + row) * 320 + k0 + g4 * 4;
      float4 f = *(const float4*)ap;
      vh4 hw;
      hw[0] = (_Float16)f.x; hw[1] = (_Float16)f.y; hw[2] = (_Float16)f.z; hw[3] = (_Float16)f.w;
      unsigned byte = (unsigned)(row * 128 + g4 * 8) ^ swzA(row);
      *(vh4*)((char*)xs + byte) = hw;
    }
    __syncthreads();
#pragma unroll
    for (int ks = 0; ks < 2; ++ks) {
      vh8 av[4], bv[5];
#pragma unroll
      for (int mt = 0; mt < 4; ++mt) {
        int row = mt * 16 + l15;
        unsigned byte = (unsigned)(row * 128 + (ks * 32 + l4 * 8) * 2) ^ swzA(row);
        av[mt] = *(const vh8*)((const char*)xs + byte);
      }
#pragma unroll
      for (int nt = 0; nt < 5; ++nt) {
        int n = wave * 80 + nt * 16 + l15;
        bv[nt] = *(const vh8*)(WqT + (size_t)n * 320 + k0 + ks * 32 + l4 * 8);
      }
#pragma unroll
      for (int mt = 0; mt < 4; ++mt)
#pragma unroll
        for (int nt = 0; nt < 5; ++nt)
          acc[mt][nt] = __builtin_amdgcn_mfma_f32_16x16x32_f16(av[mt], bv[nt], acc[mt][nt], 0, 0, 0);
    }
  }
  // epilogue: q -> qls (LDS) and qb (global)
#pragma unroll
  for (int mt = 0; mt < 4; ++mt)
#pragma unroll
    for (int nt = 0; nt < 5; ++nt) {
      int n = wave * 80 + nt * 16 + l15;
#pragma unroll
      for (int r = 0; r < 4; ++r) {
        int m = mt * 16 + l4 * 4 + r;
        _Float16 hv = (_Float16)acc[mt][nt][r];
        unsigned byte = (unsigned)(m * 640 + n * 2) ^ swzA(m);
        *(_Float16*)((char*)qls + byte) = hv;
        qb[(grow0 + m) * 320 + n] = hv;
      }
    }
  __syncthreads();

  // std part: non-swapped QK^T (A=q rows, B=K cols), masked fp64 accumulate
  double S = 0.0, S2 = 0.0;
#pragma unroll
  for (int h = 0; h < 8; ++h) {
    int qrow = wave * 16 + l15;
    unsigned qbyte0 = (unsigned)(qrow * 640 + (h * 40 + l4 * 8) * 2) ^ swzA(qrow);
    vh8 a0 = *(const vh8*)((const char*)qls + qbyte0);
    vh8 a1 = h8zero();
    if (l4 == 0) {
      unsigned qbyte1 = (unsigned)(qrow * 640 + (h * 40 + 32) * 2) ^ swzA(qrow);
      a1 = *(const vh8*)((const char*)qls + qbyte1);
    }
#pragma unroll
    for (int jt = 0; jt < 5; ++jt) {
      int j = jt * 16 + l15;
      bool valid = (j < 77);
      vh8 b0 = h8zero(), b1 = h8zero();
      int ctj = -1;
      if (valid) {
        const _Float16* kp = kf + (size_t)(b * 77 + j) * 640 + h * 40;
        b0 = *(const vh8*)(kp + l4 * 8);
        if (l4 == 0) b1 = *(const vh8*)(kp + 32);
        ctj = ctypes[b * 77 + j];
      }
      vf4 s = f4zero();
      s = __builtin_amdgcn_mfma_f32_16x16x32_f16(a0, b0, s, 0, 0, 0);
      s = __builtin_amdgcn_mfma_f32_16x16x32_f16(a1, b1, s, 0, 0, 0);
      if (ctj >= 2) {
#pragma unroll
        for (int r = 0; r < 4; ++r) {
          double sv = (double)s[r];
          S += sv; S2 += sv * sv;
        }
      }
    }
  }
#pragma unroll
  for (int off = 32; off > 0; off >>= 1) {
    S += __shfl_xor(S, off);
    S2 += __shfl_xor(S2, off);
  }
  if (lane == 0) {
    int idx = (b * 64 + it) * 4 + wave;
    partials[2 * idx + 0] = S;
    partials[2 * idx + 1] = S2;
  }
}

__global__ __launch_bounds__(256) void finalize_kernel(
    const double* __restrict__ partials, const int* __restrict__ ctypes,
    float* __restrict__ ssb)
{
  __shared__ double rs[256];
  __shared__ double rs2[256];
  __shared__ int rc[256];
  const int t = threadIdx.x;
  double S = 0.0, S2 = 0.0;
#pragma unroll
  for (int p = 0; p < 16; ++p) {
    int idx = t + p * 256;
    S += partials[2 * idx + 0];
    S2 += partials[2 * idx + 1];
  }
  int c = 0;
#pragma unroll
  for (int p = 0; p < 5; ++p) {
    int idx = t + p * 256;
    if (idx < 1232) c += (ctypes[idx] >= 2) ? 1 : 0;
  }
  rs[t] = S; rs2[t] = S2; rc[t] = c;
  __syncthreads();
  for (int off = 128; off > 0; off >>= 1) {
    if (t < off) { rs[t] += rs[t + off]; rs2[t] += rs2[t + off]; rc[t] += rc[t + off]; }
    __syncthreads();
  }
  if (t == 0) {
    double n = (double)rc[0] * 8.0 * 4096.0;
    double mean = rs[0] / n;
    double var = (rs2[0] - n * mean * mean) / (n - 1.0);
    ssb[0] = (float)sqrt(var > 0.0 ? var : 0.0);
  }
}

// ---------------------------------------------------------------------------
// attn_out: per (it,b) 64-row tile: inline lmask, loop h {QK^T, dual softmax,
// PV -> ho tile in LDS}, then fused O-projection -> d_out. Grid (64,16).
// ---------------------------------------------------------------------------
__global__ __launch_bounds__(256) void attn_out_kernel(
    const _Float16* __restrict__ q, const _Float16* __restrict__ kf,
    const unsigned* __restrict__ vTg32, const float* __restrict__ cam,
    const int* __restrict__ ctypes, const float* __restrict__ pcb,
    const float* __restrict__ ssb, const float* __restrict__ strengthp,
    const _Float16* __restrict__ WoT, const float* __restrict__ bo,
    float* __restrict__ out)
{
  __shared__ __align__(16) char hols_raw[64 * 640];  // fp16 [64][320] pitch 640B swz; cam tile alias at start
  __shared__ _Float16 vT[48 * 128];        // [d][j] pitch 256B, XOR swzA(d)
  __shared__ _Float16 attnbuf[64 * 128];   // [row][j] pitch 256B, XOR swzA(row)
  __shared__ unsigned lmw[256];
  __shared__ float gbf[96];
  __shared__ float nbf[96];

  const int t = threadIdx.x, lane = t & 63, wave = t >> 6;
  const int it = blockIdx.x, b = blockIdx.y;
  const int i0 = it * 64;
  const int l15 = lane & 15, l4 = lane >> 4;
  const size_t grow0 = (size_t)b * 4096 + i0;
  float* camt = (float*)hols_raw;          // [64][80]
  _Float16* hols = (_Float16*)hols_raw;

  if (t < 96) {
    int j = t;
    bool valid = (j < 77);
    int ct = valid ? ctypes[b * 77 + j] : -1;
    bool gm = valid && ct >= 0 && ct < 2;
    gbf[j] = gm ? 0.f : (valid ? NEGBIG : -INFF);
    nbf[j] = valid ? NEGBIG : -INFF;
  }
  // stage cam tile into hols region
#pragma unroll
  for (int p = 0; p < 20; ++p) {
    int idx = t + p * 256;
    int row = idx / 80;
    int j = idx - row * 80;
    camt[row * 80 + j] = (j < 77) ? cam[(grow0 + row) * 77 + j] : 0.f;
  }
  // zero attnbuf pad cols [80,96)
#pragma unroll
  for (int p = 0; p < 2; ++p) {
    int idx = t + p * 256;
    int row = idx >> 3, c = idx & 7;
    unsigned byte = (unsigned)(row * 256 + 160 + c * 4) ^ swzA(row);
    *(unsigned*)((char*)attnbuf + byte) = 0u;
  }
  __syncthreads();

  // inline lmask (row = t>>2, qd = t&3)
  {
    const float ss = ssb[0];
    const float st = strengthp[0];
    int row = t >> 2, qd = t & 3;
    float wfv[20];
    float wmax = 0.f, wsum = 0.f;
#pragma unroll
    for (int m = 0; m < 20; ++m) {
      int j = qd + 4 * m;
      float wf = 0.f;
      if (j < 77 && gbf[j] <= NEGBIG && nbf[j] == NEGBIG) {}   // placeholder no-op
      wfv[m] = wf;
    }
    // recompute with explicit m2 mask (ct>=2): derive from ctypes directly
#pragma unroll
    for (int m = 0; m < 20; ++m) {
      int j = qd + 4 * m;
      float wf = 0.f;
      if (j < 77) {
        int ct = ctypes[b * 77 + j];
        if (ct >= 2) wf = (camt[row * 80 + j] * ss) * st;   // ref assoc order
      }
      wfv[m] = wf;
      wmax = fmaxf(wmax, wf);
      wsum += wf;
    }
    wmax = fmaxf(wmax, __shfl_xor(wmax, 1));
    wmax = fmaxf(wmax, __shfl_xor(wmax, 2));
    wsum += __shfl_xor(wsum, 1);
    wsum += __shfl_xor(wsum, 2);
    float thr = fmaxf(wmax, 0.001f) - 0.0001f;
    bool ug = (wsum == 0.f);
    unsigned wbits = 0u;
#pragma unroll
    for (int m = 0; m < 20; ++m) {
      int j = qd + 4 * m;
      bool lv = (wfv[m] >= thr) || (ug && (j < 77) && (gbf[j] == 0.f));
      if (lv) wbits |= (1u << m);
    }
    lmw[row * 4 + qd] = wbits;
  }
  __syncthreads();

  const int myrow = wave * 16 + l15;
  unsigned wbits[4];
#pragma unroll
  for (int r = 0; r < 4; ++r) wbits[r] = lmw[myrow * 4 + r];

  for (int h = 0; h < 8; ++h) {
    // vT via glds16 (content pre-swizzled)
    {
      const unsigned* src0 = vTg32 + (size_t)(b * 8 + h) * 3072;
#pragma unroll
      for (int p = 0; p < 3; ++p) {
        int idx = t + p * 256;
        glds16(src0 + idx * 4, (char*)vT + (size_t)(p * 256 + (t & ~63)) * 16);
      }
    }
    // swapped QK^T: A=K (per-lane global), B=Q (per-lane global)
    const _Float16* qbp = q + (grow0 + wave * 16 + l15) * 320 + h * 40;
    vh8 qf0 = *(const vh8*)(qbp + l4 * 8);
    vh8 qf1 = h8zero();
    if (l4 == 0) qf1 = *(const vh8*)(qbp + 32);

    vf4 sacc[5];
#pragma unroll
    for (int jt = 0; jt < 5; ++jt) sacc[jt] = f4zero();
#pragma unroll
    for (int jt = 0; jt < 5; ++jt) {
      int j = jt * 16 + l15;
      vh8 k0v = h8zero(), k1v = h8zero();
      if (j < 77) {
        const _Float16* kp = kf + (size_t)(b * 77 + j) * 640 + h * 40;
        k0v = *(const vh8*)(kp + l4 * 8);
        if (l4 == 0) k1v = *(const vh8*)(kp + 32);
      }
      sacc[jt] = __builtin_amdgcn_mfma_f32_16x16x32_f16(k0v, qf0, sacc[jt], 0, 0, 0);
      sacc[jt] = __builtin_amdgcn_mfma_f32_16x16x32_f16(k1v, qf1, sacc[jt], 0, 0, 0);
    }

    // in-lane dual softmax
    const float pc0 = pcb[(b * 8 + h) * 2 + 0];
    const float pc1 = pcb[(b * 8 + h) * 2 + 1];
    float gv[5][4], lv[5][4];
    float mg = -INFF, ml = -INFF;
#pragma unroll
    for (int jt = 0; jt < 5; ++jt) {
      int jbase = jt * 16 + l4 * 4;
      float4 gb4 = *(const float4*)&gbf[jbase];
      float4 nb4 = *(const float4*)&nbf[jbase];
      const float* gbp = (const float*)&gb4;
      const float* nbp = (const float*)&nb4;
#pragma unroll
      for (int r = 0; r < 4; ++r) {
        float sv = sacc[jt][r];
        float g = fmaf(sv, SC2, gbp[r]);
        unsigned bit = (wbits[r] >> (jt * 4 + l4)) & 1u;
        float l = fmaf(sv, SC2, bit ? 0.f : nbp[r]);
        gv[jt][r] = g; lv[jt][r] = l;
        mg = fmaxf(mg, g); ml = fmaxf(ml, l);
      }
    }
    mg = fmaxf(mg, __shfl_xor(mg, 16)); mg = fmaxf(mg, __shfl_xor(mg, 32));
    ml = fmaxf(ml, __shfl_xor(ml, 16)); ml = fmaxf(ml, __shfl_xor(ml, 32));
    float sG = 0.f, sL = 0.f;
#pragma unroll
    for (int jt = 0; jt < 5; ++jt)
#pragma unroll
      for (int r = 0; r < 4; ++r) {
        float eg = exp2f(gv[jt][r] - mg);
        float el = exp2f(lv[jt][r] - ml);
        gv[jt][r] = eg; lv[jt][r] = el;
        sG += eg; sL += el;
      }
    sG += __shfl_xor(sG, 16); sG += __shfl_xor(sG, 32);
    sL += __shfl_xor(sL, 16); sL += __shfl_xor(sL, 32);
    float rG = pc0 / sG, rL = pc1 / sL;
    {
      unsigned swz = swzA(myrow);
      unsigned rowbase = (unsigned)(myrow * 256);
#pragma unroll
      for (int jt = 0; jt < 5; ++jt) {
        vh4 w;
#pragma unroll
        for (int r = 0; r < 4; ++r)
          w[r] = (_Float16)fmaf(gv[jt][r], rG, lv[jt][r] * rL);
        unsigned byte = (rowbase + (unsigned)((jt * 16 + l4 * 4) * 2)) ^ swz;
        *(vh4*)((char*)attnbuf + byte) = w;
      }
    }
    __syncthreads();   // attnbuf written, vT loaded

    // PV MFMA -> hols slice
    vf4 oacc[3];
#pragma unroll
    for (int nt = 0; nt < 3; ++nt) oacc[nt] = f4zero();
#pragma unroll
    for (int ks = 0; ks < 3; ++ks) {
      int arow = wave * 16 + l15;
      unsigned abyte = (unsigned)(arow * 256 + (ks * 32 + l4 * 8) * 2) ^ swzA(arow);
      vh8 pa = *(const vh8*)((const char*)attnbuf + abyte);
#pragma unroll
      for (int nt = 0; nt < 3; ++nt) {
        int n = nt * 16 + l15;
        unsigned byte = (unsigned)(n * 256 + (ks * 32 + l4 * 8) * 2) ^ swzA(n);
        vh8 vb = *(const vh8*)((const char*)vT + byte);
        oacc[nt] = __builtin_amdgcn_mfma_f32_16x16x32_f16(pa, vb, oacc[nt], 0, 0, 0);
      }
    }
#pragma unroll
    for (int nt = 0; nt < 3; ++nt) {
      int d = nt * 16 + l15;
      if (d < 40) {
#pragma unroll
        for (int r = 0; r < 4; ++r) {
          int row = wave * 16 + l4 * 4 + r;
          unsigned byte = (unsigned)(row * 640 + (h * 40 + d) * 2) ^ swzA(row);
          *(_Float16*)((char*)hols + byte) = (_Float16)oacc[nt][r];
        }
      }
    }
    __syncthreads();   // hols slice done; vT/attnbuf safe to overwrite
  }

  // fused O-projection: out[64,320] = hols[64,320] @ WoT[320,320]^T + bo
  vf4 oa[4][5];
#pragma unroll
  for (int a = 0; a < 4; ++a)
#pragma unroll
    for (int bq = 0; bq < 5; ++bq) oa[a][bq] = f4zero();
#pragma unroll
  for (int kc = 0; kc < 10; ++kc) {
    vh8 av[4], bv[5];
#pragma unroll
    for (int mt = 0; mt < 4; ++mt) {
      int row = mt * 16 + l15;
      unsigned byte = (unsigned)(row * 640 + (kc * 32 + l4 * 8) * 2) ^ swzA(row);
      av[mt] = *(const vh8*)((const char*)hols + byte);
    }
#pragma unroll
    for (int nt = 0; nt < 5; ++nt) {
      int n = wave * 80 + nt * 16 + l15;
      bv[nt] = *(const vh8*)(WoT + (size_t)n * 320 + kc * 32 + l4 * 8);
    }
#pragma unroll
    for (int mt = 0; mt < 4; ++mt)
#pragma unroll
      for (int nt = 0; nt < 5; ++nt)
        oa[mt][nt] = __builtin_amdgcn_mfma_f32_16x16x32_f16(av[mt], bv[nt], oa[mt][nt], 0, 0, 0);
  }
#pragma unroll
  for (int mt = 0; mt < 4; ++mt)
#pragma unroll
    for (int nt = 0; nt < 5; ++nt) {
      int n = wave * 80 + nt * 16 + l15;
      float bias = bo[n];
#pragma unroll
      for (int r = 0; r < 4; ++r) {
        int m = mt * 16 + l4 * 4 + r;
        out[(grow0 + m) * 320 + n] = oa[mt][nt][r] + bias;
      }
    }
}

// ---------------------------------------------------------------------------
extern "C" void kernel_launch(void* const* d_in, const int* in_sizes, int n_in,
                              void* d_out, int out_size, void* d_ws, size_t ws_size,
                              hipStream_t stream)
{
  const float* x        = (const float*)d_in[0];
  const float* embs     = (const float*)d_in[1];
  const float* cam      = (const float*)d_in[2];
  const float* progress = (const float*)d_in[3];
  const float* strength = (const float*)d_in[4];
  const float* Wq       = (const float*)d_in[5];
  const float* Wk       = (const float*)d_in[6];
  const float* Wv       = (const float*)d_in[7];
  const float* Wo       = (const float*)d_in[8];
  const float* bo       = (const float*)d_in[9];
  const float* emb1     = (const float*)d_in[10];
  const float* emb2     = (const float*)d_in[11];
  const float* Wc1      = (const float*)d_in[12];
  const float* bc1      = (const float*)d_in[13];
  const float* Wc2      = (const float*)d_in[14];
  const float* bc2      = (const float*)d_in[15];
  const int*   ctypes   = (const int*)d_in[16];

  char* w = (char*)d_ws;
  auto alloc = [&](size_t bytes) { char* p = w; w += (bytes + 255) & ~(size_t)255; return p; };
  _Float16* qb    = (_Float16*)alloc(65536ull * 320 * 2);   // 40 MiB
  _Float16* kvb   = (_Float16*)alloc(1232ull * 640 * 2);    // 1.5 MiB
  unsigned* vTg   = (unsigned*)alloc(128ull * 3072 * 4);    // 1.5 MiB
  _Float16* WqT   = (_Float16*)alloc(320ull * 320 * 2);
  _Float16* WkvT  = (_Float16*)alloc(640ull * 768 * 2);
  _Float16* WoT   = (_Float16*)alloc(320ull * 320 * 2);
  float*    pcb   = (float*)alloc(256 * 4);
  double*   part  = (double*)alloc(4096ull * 2 * 8);        // 64 KiB
  float*    ssb   = (float*)alloc(256);

  transpose_kernel<<<2720, 256, 0, stream>>>(Wq, Wk, Wv, Wo, WqT, WkvT, WoT);
  classifier_kernel<<<16, 256, 0, stream>>>(progress, emb1, emb2, Wc1, bc1, Wc2, bc2, pcb);
  kv_gemm_kernel<<<dim3(10, 4), 256, 0, stream>>>(embs, WkvT, kvb, 1232, 640, 768);
  vtrans_kernel<<<dim3(16, 8), 256, 0, stream>>>(kvb + 320, vTg);
  qstd_kernel<<<dim3(64, 16), 256, 0, stream>>>(x, WqT, kvb, ctypes, qb, part);
  finalize_kernel<<<1, 256, 0, stream>>>(part, ctypes, ssb);
  attn_out_kernel<<<dim3(64, 16), 256, 0, stream>>>(qb, kvb, vTg, cam, ctypes, pcb, ssb, strength,
                                                    WoT, bo, (float*)d_out);
}